// Round 9
// baseline (323.501 us; speedup 1.0000x reference)
//
#include <hip/hip_runtime.h>

typedef __attribute__((ext_vector_type(8))) __bf16 bf16x8;
typedef __attribute__((ext_vector_type(4))) float f32x4;
typedef __attribute__((ext_vector_type(16))) float f32x16;
typedef __attribute__((ext_vector_type(8))) unsigned short u16x8;
typedef __attribute__((ext_vector_type(4))) unsigned short u16x4;
typedef __attribute__((ext_vector_type(2))) unsigned int u32x2;
typedef __attribute__((ext_vector_type(4))) unsigned int u32x4;

#define MFMA16(a, b, c) __builtin_amdgcn_mfma_f32_16x16x32_bf16((a), (b), (c), 0, 0, 0)
#define MFMA32(a, b, c) __builtin_amdgcn_mfma_f32_32x32x16_bf16((a), (b), (c), 0, 0, 0)
#define WAITVM(n) asm volatile("s_waitcnt vmcnt(" #n ")" ::: "memory")

__device__ __forceinline__ unsigned short f2bf(float f) {
    unsigned int u = __float_as_uint(f);
    unsigned int r = (u + 0x7FFFu + ((u >> 16) & 1u)) >> 16;
    return (unsigned short)r;
}

__device__ __forceinline__ float fexp2(float x) {
#if __has_builtin(__builtin_amdgcn_exp2f)
    return __builtin_amdgcn_exp2f(x);
#else
    return exp2f(x);
#endif
}

// gfx950 lane-swap primitives (half-wave data movement without LDS).
__device__ __forceinline__ u32x2 plswap32(unsigned int x, unsigned int y) {
#if __has_builtin(__builtin_amdgcn_permlane32_swap)
    return __builtin_amdgcn_permlane32_swap(x, y, false, false);
#else
    asm volatile("s_nop 1\n\tv_permlane32_swap_b32 %0, %1" : "+v"(x), "+v"(y));
    u32x2 r = {x, y};
    return r;
#endif
}

// ---------------- fused prep: x->bf16 convert + 4 weight transposes ----------------
__device__ __forceinline__ void transpose_tile(const float* __restrict__ in,
                                               unsigned short* __restrict__ out,
                                               int R, int C, int bx, int by) {
    __shared__ float tile[32][33];
    const int tx = threadIdx.x & 31, ty = threadIdx.x >> 5;
    const int c0 = bx * 32, r0 = by * 32;
#pragma unroll
    for (int i = 0; i < 4; ++i)
        tile[ty + i * 8][tx] = in[(size_t)(r0 + ty + i * 8) * C + c0 + tx];
    __syncthreads();
#pragma unroll
    for (int i = 0; i < 4; ++i)
        out[(size_t)(c0 + ty + i * 8) * R + r0 + tx] = f2bf(tile[tx][ty + i * 8]);
}

__global__ __launch_bounds__(256) void k_prep(const float* __restrict__ x,
                                              const float* __restrict__ Wq,
                                              const float* __restrict__ Wkvd,
                                              const float* __restrict__ Wkvu,
                                              const float* __restrict__ Wo,
                                              unsigned short* __restrict__ xb,
                                              unsigned short* __restrict__ Wcat_t,
                                              unsigned short* __restrict__ Wkvu_t,
                                              unsigned short* __restrict__ Wo_t) {
    const int i = blockIdx.x;
    if (i < 8192) {
        const int idx = i * 256 + threadIdx.x;
        const float4 v = ((const float4*)x)[idx];
        u16x4 o = { f2bf(v.x), f2bf(v.y), f2bf(v.z), f2bf(v.w) };
        ((u16x4*)xb)[idx] = o;
    } else if (i < 12288) {
        const int j = i - 8192;
        transpose_tile(Wq, Wcat_t, 2048, 2048, j & 63, j >> 6);
    } else if (i < 13312) {
        const int j = i - 12288;
        transpose_tile(Wkvd, Wcat_t + 2048 * 2048, 2048, 512, j & 15, j >> 4);
    } else if (i < 14336) {
        const int j = i - 13312;
        transpose_tile(Wkvu, Wkvu_t, 512, 2048, j & 63, j >> 6);
    } else {
        const int j = i - 14336;
        transpose_tile(Wo, Wo_t, 2048, 2048, j & 63, j >> 6);
    }
}

// ---------------- bf16 GEMM (m97 128^2 structure) -- used for gemm2 only ----------
// OUT_MODE: 2 = bf16 C + transposed copy Ct (per-head d-major).
template <int OUT_MODE>
__global__ __launch_bounds__(256) void k_gemm_bt(const unsigned short* __restrict__ A,
                                                 const unsigned short* __restrict__ B,
                                                 void* __restrict__ Cv,
                                                 unsigned short* __restrict__ Ct,
                                                 int M, int N, int K, float alpha) {
    __shared__ alignas(16) unsigned short As[2 * 128 * 32];
    __shared__ alignas(16) unsigned short Bs[2 * 128 * 32];
    const int tid = threadIdx.x;
    const int wave = tid >> 6;
    const int lane = tid & 63;
    const int l16 = lane & 15;
    const int quad = lane >> 4;
    const int bm = blockIdx.x * 128;
    const int bn = blockIdx.y * 128;
    const int wm = (wave >> 1) * 64;
    const int wn = (wave & 1) * 64;

    const f32x4 fzero = {0.f, 0.f, 0.f, 0.f};
    f32x4 acc[4][4];
#pragma unroll
    for (int i = 0; i < 4; ++i)
#pragma unroll
        for (int j = 0; j < 4; ++j) acc[i][j] = fzero;

    auto AsL = (__attribute__((address_space(3))) unsigned short*)As;
    auto BsL = (__attribute__((address_space(3))) unsigned short*)Bs;

    const int c0 = wave * 128 + lane;

    auto stage = [&](int kt32) {
        const int boff = (kt32 & 1) * (128 * 32);
        const int kt = kt32 * 32;
#pragma unroll
        for (int j = 0; j < 2; ++j) {
            const int c = c0 + j * 64;
            __builtin_amdgcn_global_load_lds(
                (const __attribute__((address_space(1))) void*)(A + (size_t)(bm + (c >> 2)) * K + kt + (c & 3) * 8),
                (__attribute__((address_space(3))) void*)(AsL + boff + c * 8), 16, 0, 0);
            __builtin_amdgcn_global_load_lds(
                (const __attribute__((address_space(1))) void*)(B + (size_t)(bn + (c >> 2)) * K + kt + (c & 3) * 8),
                (__attribute__((address_space(3))) void*)(BsL + boff + c * 8), 16, 0, 0);
        }
    };

    const int nk = K >> 5;
    stage(0);
    for (int kt32 = 0; kt32 < nk; ++kt32) {
        __syncthreads();
        if (kt32 + 1 < nk) stage(kt32 + 1);
        const unsigned short* Ab = As + (kt32 & 1) * (128 * 32);
        const unsigned short* Bb = Bs + (kt32 & 1) * (128 * 32);

        bf16x8 af[4], bfr[4];
#pragma unroll
        for (int mt = 0; mt < 4; ++mt)
            af[mt] = *(const bf16x8*)(Ab + (wm + mt * 16 + l16) * 32 + quad * 8);
#pragma unroll
        for (int nt = 0; nt < 4; ++nt)
            bfr[nt] = *(const bf16x8*)(Bb + (wn + nt * 16 + l16) * 32 + quad * 8);
#pragma unroll
        for (int mt = 0; mt < 4; ++mt)
#pragma unroll
            for (int nt = 0; nt < 4; ++nt)
                acc[mt][nt] = MFMA16(af[mt], bfr[nt], acc[mt][nt]);
    }

#pragma unroll
    for (int mt = 0; mt < 4; ++mt)
#pragma unroll
        for (int nt = 0; nt < 4; ++nt) {
            const int row0 = bm + wm + mt * 16 + quad * 4;
            const int col = bn + wn + nt * 16 + l16;
            u16x4 pk;
#pragma unroll
            for (int r = 0; r < 4; ++r) {
                const float v0 = acc[mt][nt][r];
                const unsigned short b = f2bf(v0 * alpha);
                ((unsigned short*)Cv)[(size_t)(row0 + r) * N + col] = b;
                pk[r] = b;
            }
            if (OUT_MODE == 2) {
                const size_t ti =
                    ((size_t)((row0 >> 11) * (N >> 7) + (col >> 7)) * 128 + (col & 127)) * 2048 +
                    (row0 & 2047);
                *(u16x4*)(Ct + ti) = pk;
            }
        }
}

// ---------------- 256^2 bf16 GEMM: 3-deep LDS ring + counted vmcnt ----------------
// R16: breaks the m97 drain-stall (the documented ~20% ceiling mechanism): 3 buffers
// of BK=32 -> stage(kt+2) targets the buffer whose readers crossed the barrier two
// iterations ago (race-free with ONE plain s_barrier/tile); "s_waitcnt vmcnt(4)"
// at the top waits only tile kt's 4 loads -- tile kt+1's stay in flight ACROSS the
// barrier (R14 ledger pattern; each load gets ~2 full tiles to fly >> 900cyc HBM).
// [m131-m140: with 2 buffers this is impossible -- the incoming tile must drain.]
// Tile 256x256, 8 waves (2M x 4N), per-wave 128x64 = 8x4 frags: 12 ds_read_b128
// per 32 MFMA (0.375 vs m97's 0.5). LDS = 3*(16+16)KB = 96KB dynamic, 1 block/CU.
// Swizzle (both-sides involution, rule 21): chunk ^= ((r>>3)&1)<<1 ^ ((r>>1)&1)
// applied to the pre-swizzled global source and the frag-read -- bank-checked:
// lanes/(parity,chunk) = 2 -> 2-way = free (m97's linear layout is 8-way).
// vmcnt ledger (4 gload_lds/stage): prologue 8; steady wait(4); tail wait(0).
// OUT_MODE: 0 = fp32 C*alpha; 3 = fused split (col<2048 -> bf16*alpha; else Ct).
template <int OUT_MODE>
__global__ __launch_bounds__(512, 2) void k_gemm256(const unsigned short* __restrict__ A,
                                                    const unsigned short* __restrict__ B,
                                                    void* __restrict__ Cv,
                                                    unsigned short* __restrict__ Ct,
                                                    int M, int N, int K, float alpha) {
    extern __shared__ unsigned short sm[];  // [3][256][32] A then [3][256][32] B
    unsigned short* As = sm;
    unsigned short* Bs = sm + 3 * 256 * 32;
    const int tid = threadIdx.x;
    const int wave = tid >> 6;
    const int lane = tid & 63;
    const int l16 = lane & 15;
    const int quad = lane >> 4;
    const int bm = blockIdx.x * 256;
    const int bn = blockIdx.y * 256;
    const int wm = (wave >> 2) * 128;  // 2 M-halves
    const int wn = (wave & 3) * 64;    // 4 N-quarters

    const f32x4 fzero = {0.f, 0.f, 0.f, 0.f};
    f32x4 acc[8][4];
#pragma unroll
    for (int i = 0; i < 8; ++i)
#pragma unroll
        for (int j = 0; j < 4; ++j) acc[i][j] = fzero;

    auto AsL = (__attribute__((address_space(3))) unsigned short*)As;
    auto BsL = (__attribute__((address_space(3))) unsigned short*)Bs;

    // staging: slot = p*512+tid; row r = slot>>2 (p*128 + tid>>2), chunk = slot&3.
    // source chunk pre-swizzled: cs = (tid&3) ^ ((tid>>5)&1)<<1 ^ ((tid>>3)&1)
    // (r's bits 3 and 1 are p-invariant: r = p*128 + (tid>>2)).
    const int rstage = tid >> 2;
    const int cs = (tid & 3) ^ (((tid >> 5) & 1) << 1) ^ ((tid >> 3) & 1);
    const unsigned short* ap0 = A + (size_t)(bm + rstage) * K + cs * 8;
    const unsigned short* bp0 = B + (size_t)(bn + rstage) * K + cs * 8;

    auto stage = [&](int kt) {
        const int buf = kt % 3;
        auto Ad = AsL + buf * 8192 + tid * 8;
        auto Bd = BsL + buf * 8192 + tid * 8;
        const unsigned short* ap = ap0 + kt * 32;
        const unsigned short* bp = bp0 + kt * 32;
#pragma unroll
        for (int p = 0; p < 2; ++p) {
            __builtin_amdgcn_global_load_lds(
                (const __attribute__((address_space(1))) void*)(ap + (size_t)p * 128 * K),
                (__attribute__((address_space(3))) void*)(Ad + p * 4096), 16, 0, 0);
            __builtin_amdgcn_global_load_lds(
                (const __attribute__((address_space(1))) void*)(bp + (size_t)p * 128 * K),
                (__attribute__((address_space(3))) void*)(Bd + p * 4096), 16, 0, 0);
        }
    };

    // frag-read chunk (same involution; row bits 3,1 of (wm+mf*16+l16) are l16's)
    const int cq = quad ^ (((l16 >> 3) & 1) << 1) ^ ((l16 >> 1) & 1);

    const int nk = K >> 5;
    stage(0);
    stage(1);

    for (int kt = 0; kt < nk; ++kt) {
        if (kt + 1 < nk) { WAITVM(4); } else { WAITVM(0); }
        __builtin_amdgcn_s_barrier();
        if (kt + 2 < nk) stage(kt + 2);

        const unsigned short* Ab = As + (kt % 3) * 8192;
        const unsigned short* Bb = Bs + (kt % 3) * 8192;

        bf16x8 af[8], bfr[4];
#pragma unroll
        for (int mf = 0; mf < 8; ++mf)
            af[mf] = *(const bf16x8*)(Ab + (wm + mf * 16 + l16) * 32 + cq * 8);
#pragma unroll
        for (int nf = 0; nf < 4; ++nf)
            bfr[nf] = *(const bf16x8*)(Bb + (wn + nf * 16 + l16) * 32 + cq * 8);

        __builtin_amdgcn_s_setprio(1);
#pragma unroll
        for (int mf = 0; mf < 8; ++mf)
#pragma unroll
            for (int nf = 0; nf < 4; ++nf)
                acc[mf][nf] = MFMA16(af[mf], bfr[nf], acc[mf][nf]);
        __builtin_amdgcn_s_setprio(0);
    }

#pragma unroll
    for (int mf = 0; mf < 8; ++mf)
#pragma unroll
        for (int nf = 0; nf < 4; ++nf) {
            const int row0 = bm + wm + mf * 16 + quad * 4;
            const int col = bn + wn + nf * 16 + l16;
#pragma unroll
            for (int r = 0; r < 4; ++r) {
                const float v0 = acc[mf][nf][r];
                if (OUT_MODE == 0) {
                    ((float*)Cv)[(size_t)(row0 + r) * N + col] = v0 * alpha;
                } else {
                    if (col < 2048)
                        ((unsigned short*)Cv)[(size_t)(row0 + r) * 2048 + col] = f2bf(v0 * alpha);
                    else
                        Ct[(size_t)(row0 + r) * 512 + (col - 2048)] = f2bf(v0);
                }
            }
        }
}

// ---------------- flash attention (R15, frozen: 81.8us = structure ceiling) -------
// 32x32x16 MFMA on the R12 skeleton (KVBLK=64, 2-deep dbuf, __syncthreads,
// gload_lds + pre-swizzled sources). In-register P via cvt_pk + permlane32.
// [R11-R15 lessons: VALU/issue trims, gload_lds, KVBLK=32 pipeline, counted vmcnt,
//  MFMA shape -- all pin at ~82us: latency-bound at structural 2 waves/SIMD.]
// Grid (16 qt, 32 bh) XCD-chunked; 4 waves; wave owns 32 q-rows; 2 blk/CU; LDS 64K.
// Base-2 no-max softmax (log2e folded into q). Writes output IN-PLACE over Q.
__global__ __launch_bounds__(256, 2) void k_attn(const unsigned short* __restrict__ Q,
                                                 const unsigned short* __restrict__ KV,
                                                 const unsigned short* __restrict__ KVT,
                                                 unsigned short* __restrict__ O) {
    __shared__ alignas(16) unsigned short Ks[2 * 64 * 128];   // [buf][kr][d], swizzled
    __shared__ alignas(16) unsigned short Vt[2 * 128 * 64];   // [buf][d][kr], swizzled

    const int tid = threadIdx.x;
    const int wave = tid >> 6, lane = tid & 63;
    const int q31 = lane & 31;
    const int hi = lane >> 5;
    const int l8 = q31 & 7;
    const int lid = blockIdx.x + (blockIdx.y << 4);
    const int wid = ((lid & 7) << 6) + (lid >> 3);
    const int qt = wid & 15;
    const int bh = wid >> 4;
    const size_t tokbase = (size_t)(bh >> 4) * 2048;
    const int hcol = (bh & 15) * 128;
    const unsigned short* kvt_head = KVT + (size_t)bh * (128 * 2048);

    bf16x8 qf[8];
    const int qrow0 = qt * 128 + wave * 32;
    {
        const unsigned short* qp = Q + (tokbase + qrow0 + q31) * 2048 + hcol + hi * 8;
#pragma unroll
        for (int kd = 0; kd < 8; ++kd) qf[kd] = *(const bf16x8*)(qp + kd * 16);
    }

    f32x16 o_acc[4];
#pragma unroll
    for (int dt = 0; dt < 4; ++dt)
#pragma unroll
        for (int r = 0; r < 16; ++r) o_acc[dt][r] = 0.f;
    float l_i = 0.f;

    auto KsL = (__attribute__((address_space(3))) unsigned short*)Ks;
    auto VtL = (__attribute__((address_space(3))) unsigned short*)Vt;

    const int r4 = tid >> 4, cdK = tid & 15;
    const int csK = (cdK & 8) | ((cdK & 7) ^ (r4 & 7));
    const int dv = tid >> 3, cvV = tid & 7;
    const int csV = cvV ^ (dv & 7);
    const unsigned short* kp0 = KV + (tokbase + r4) * 2048 + hcol + csK * 8;
    const unsigned short* vp0 = kvt_head + (size_t)dv * 2048 + csV * 8;

    auto stage = [&](int kt) {
        auto Kb = KsL + (kt & 1) * (64 * 128) + tid * 8;
        auto Vb = VtL + (kt & 1) * (128 * 64) + tid * 8;
        const unsigned short* kp = kp0 + (size_t)kt * (64 * 2048);
        const unsigned short* vp = vp0 + kt * 64;
#pragma unroll
        for (int p = 0; p < 4; ++p) {
            __builtin_amdgcn_global_load_lds(
                (const __attribute__((address_space(1))) void*)(kp + p * (16 * 2048)),
                (__attribute__((address_space(3))) void*)(Kb + p * 2048), 16, 0, 0);
            __builtin_amdgcn_global_load_lds(
                (const __attribute__((address_space(1))) void*)(vp + (size_t)p * (32 * 2048)),
                (__attribute__((address_space(3))) void*)(Vb + p * 2048), 16, 0, 0);
        }
    };

    stage(0);

    for (int kt = 0; kt < 32; ++kt) {
        __syncthreads();
        if (kt < 31) stage(kt + 1);
        const unsigned short* Kb = Ks + (kt & 1) * (64 * 128);
        const unsigned short* Vb = Vt + (kt & 1) * (128 * 64);

        f32x16 st[2];
#pragma unroll
        for (int r = 0; r < 16; ++r) { st[0][r] = 0.f; st[1][r] = 0.f; }
        __builtin_amdgcn_s_setprio(1);
#pragma unroll
        for (int kd = 0; kd < 8; ++kd) {
            const int c = 2 * kd + hi;
            const int sw = (c & 8) | ((c & 7) ^ l8);
#pragma unroll
            for (int mt = 0; mt < 2; ++mt) {
                const bf16x8 kf = *(const bf16x8*)(Kb + (mt * 32 + q31) * 128 + sw * 8);
                st[mt] = MFMA32(kf, qf[kd], st[mt]);
            }
        }
        __builtin_amdgcn_s_setprio(0);

        bf16x8 pfrk[2][2];
#pragma unroll
        for (int mt = 0; mt < 2; ++mt) {
            float p[16];
            float rs = 0.f;
#pragma unroll
            for (int r = 0; r < 16; ++r) {
                p[r] = fexp2(st[mt][r]);
                rs += p[r];
            }
            l_i += rs;
#pragma unroll
            for (int s = 0; s < 2; ++s) {
                unsigned int w0, w1, w2, w3;
                asm("v_cvt_pk_bf16_f32 %0, %1, %2" : "=v"(w0) : "v"(p[s * 8 + 0]), "v"(p[s * 8 + 1]));
                asm("v_cvt_pk_bf16_f32 %0, %1, %2" : "=v"(w1) : "v"(p[s * 8 + 2]), "v"(p[s * 8 + 3]));
                asm("v_cvt_pk_bf16_f32 %0, %1, %2" : "=v"(w2) : "v"(p[s * 8 + 4]), "v"(p[s * 8 + 5]));
                asm("v_cvt_pk_bf16_f32 %0, %1, %2" : "=v"(w3) : "v"(p[s * 8 + 6]), "v"(p[s * 8 + 7]));
                const u32x2 u02 = plswap32(w0, w2);
                const u32x2 u13 = plswap32(w1, w3);
                const u32x4 w = {u02.x, u13.x, u02.y, u13.y};
                pfrk[mt][s] = __builtin_bit_cast(bf16x8, w);
            }
        }

        __builtin_amdgcn_s_setprio(1);
#pragma unroll
        for (int ks = 0; ks < 4; ++ks) {
            const int swv = ((2 * ks + hi) ^ l8) * 8;
            const bf16x8 pf = pfrk[ks >> 1][ks & 1];
#pragma unroll
            for (int dt = 0; dt < 4; ++dt) {
                const bf16x8 vf = *(const bf16x8*)(Vb + (dt * 32 + q31) * 64 + swv);
                o_acc[dt] = MFMA32(vf, pf, o_acc[dt]);
            }
        }
        __builtin_amdgcn_s_setprio(0);
    }

    {
        const u32x2 a = plswap32(__float_as_uint(l_i), __float_as_uint(l_i));
        const float inv = 1.0f / (__uint_as_float(a.x) + __uint_as_float(a.y));
        unsigned short* dst = O + (tokbase + qrow0 + q31) * 2048 + hcol + hi * 4;
#pragma unroll
        for (int dt = 0; dt < 4; ++dt)
#pragma unroll
            for (int g = 0; g < 4; ++g) {
                u16x4 pk;
#pragma unroll
                for (int j = 0; j < 4; ++j) pk[j] = f2bf(o_acc[dt][g * 4 + j] * inv);
                *(u16x4*)(dst + dt * 32 + g * 8) = pk;
            }
    }
}

// ---------------- host launcher ----------------
extern "C" void kernel_launch(void* const* d_in, const int* in_sizes, int n_in,
                              void* d_out, int out_size, void* d_ws, size_t ws_size,
                              hipStream_t stream) {
    const float* x = (const float*)d_in[0];
    const float* W_q = (const float*)d_in[1];
    const float* W_kvd = (const float*)d_in[2];
    const float* W_kvu = (const float*)d_in[3];
    const float* W_o = (const float*)d_in[4];

    char* w = (char*)d_ws;
    unsigned short* xb = (unsigned short*)(w);
    unsigned short* kvT = xb;
    unsigned short* qb = (unsigned short*)(w + (size_t)16 * 1024 * 1024);
    unsigned short* kvb = (unsigned short*)(w + (size_t)32 * 1024 * 1024);
    unsigned short* Wo_t = (unsigned short*)(w + (size_t)48 * 1024 * 1024);
    unsigned short* Wcat_t = (unsigned short*)(w + (size_t)56 * 1024 * 1024);
    unsigned short* Wkvu_t = (unsigned short*)(w + (size_t)66 * 1024 * 1024);
    unsigned short* lat = (unsigned short*)(w + (size_t)68 * 1024 * 1024);

    // allow 96KB dynamic LDS on the 256^2 GEMMs (one-time host attribute; captured)
    static bool attr_done = false;
    if (!attr_done) {
        hipFuncSetAttribute(reinterpret_cast<const void*>(k_gemm256<3>),
                            hipFuncAttributeMaxDynamicSharedMemorySize, 98304);
        hipFuncSetAttribute(reinterpret_cast<const void*>(k_gemm256<0>),
                            hipFuncAttributeMaxDynamicSharedMemorySize, 98304);
        attr_done = true;
    }

    // fused prep: x->bf16 + all weight transposes (one dispatch)
    k_prep<<<18432, 256, 0, stream>>>(x, W_q, W_kvd, W_kvu, W_o, xb, Wcat_t, Wkvu_t, Wo_t);

    // fused: q = (x@W_q)*(scale*log2e) -> qb ; latent = x@W_kv_down -> lat
    // R16: 256^2 3-ring counted-vmcnt GEMM (16x10 WGs)
    k_gemm256<3><<<dim3(16, 10), 512, 98304, stream>>>(xb, Wcat_t, qb, lat, 4096, 2560,
                                                       2048, 0.12751743f);
    // kv = latent @ W_kv_up (+ per-head transposed copy kvT); K=512 stays on m97 kernel
    k_gemm_bt<2><<<dim3(32, 16), 256, 0, stream>>>(lat, Wkvu_t, kvb, kvT, 4096, 2048, 512,
                                                   1.0f);
    // flash attention (output in-place over qb); R15 config (frozen)
    k_attn<<<dim3(16, 32), 256, 0, stream>>>(qb, kvb, kvT, qb);
    // out = attn @ W_o  (fp32 output); R16: 256^2 3-ring GEMM (16x8 WGs)
    k_gemm256<0><<<dim3(16, 8), 512, 98304, stream>>>(qb, Wo_t, d_out, nullptr, 4096, 2048,
                                                      2048, 1.0f);
}

// Round 10
// 312.966 us; speedup vs baseline: 1.0337x; 1.0337x over previous
//
#include <hip/hip_runtime.h>

typedef __attribute__((ext_vector_type(8))) __bf16 bf16x8;
typedef __attribute__((ext_vector_type(4))) float f32x4;
typedef __attribute__((ext_vector_type(16))) float f32x16;
typedef __attribute__((ext_vector_type(8))) unsigned short u16x8;
typedef __attribute__((ext_vector_type(4))) unsigned short u16x4;
typedef __attribute__((ext_vector_type(2))) unsigned int u32x2;
typedef __attribute__((ext_vector_type(4))) unsigned int u32x4;

#define MFMA16(a, b, c) __builtin_amdgcn_mfma_f32_16x16x32_bf16((a), (b), (c), 0, 0, 0)
#define MFMA32(a, b, c) __builtin_amdgcn_mfma_f32_32x32x16_bf16((a), (b), (c), 0, 0, 0)
#define WAITVM(n) asm volatile("s_waitcnt vmcnt(" #n ")" ::: "memory")

__device__ __forceinline__ unsigned short f2bf(float f) {
    unsigned int u = __float_as_uint(f);
    unsigned int r = (u + 0x7FFFu + ((u >> 16) & 1u)) >> 16;
    return (unsigned short)r;
}

__device__ __forceinline__ float fexp2(float x) {
#if __has_builtin(__builtin_amdgcn_exp2f)
    return __builtin_amdgcn_exp2f(x);
#else
    return exp2f(x);
#endif
}

// gfx950 lane-swap primitives (half-wave data movement without LDS).
__device__ __forceinline__ u32x2 plswap32(unsigned int x, unsigned int y) {
#if __has_builtin(__builtin_amdgcn_permlane32_swap)
    return __builtin_amdgcn_permlane32_swap(x, y, false, false);
#else
    asm volatile("s_nop 1\n\tv_permlane32_swap_b32 %0, %1" : "+v"(x), "+v"(y));
    u32x2 r = {x, y};
    return r;
#endif
}

// ---------------- fused prep: x->bf16 convert + 4 weight transposes ----------------
__device__ __forceinline__ void transpose_tile(const float* __restrict__ in,
                                               unsigned short* __restrict__ out,
                                               int R, int C, int bx, int by) {
    __shared__ float tile[32][33];
    const int tx = threadIdx.x & 31, ty = threadIdx.x >> 5;
    const int c0 = bx * 32, r0 = by * 32;
#pragma unroll
    for (int i = 0; i < 4; ++i)
        tile[ty + i * 8][tx] = in[(size_t)(r0 + ty + i * 8) * C + c0 + tx];
    __syncthreads();
#pragma unroll
    for (int i = 0; i < 4; ++i)
        out[(size_t)(c0 + ty + i * 8) * R + r0 + tx] = f2bf(tile[tx][ty + i * 8]);
}

__global__ __launch_bounds__(256) void k_prep(const float* __restrict__ x,
                                              const float* __restrict__ Wq,
                                              const float* __restrict__ Wkvd,
                                              const float* __restrict__ Wkvu,
                                              const float* __restrict__ Wo,
                                              unsigned short* __restrict__ xb,
                                              unsigned short* __restrict__ Wcat_t,
                                              unsigned short* __restrict__ Wkvu_t,
                                              unsigned short* __restrict__ Wo_t) {
    const int i = blockIdx.x;
    if (i < 8192) {
        const int idx = i * 256 + threadIdx.x;
        const float4 v = ((const float4*)x)[idx];
        u16x4 o = { f2bf(v.x), f2bf(v.y), f2bf(v.z), f2bf(v.w) };
        ((u16x4*)xb)[idx] = o;
    } else if (i < 12288) {
        const int j = i - 8192;
        transpose_tile(Wq, Wcat_t, 2048, 2048, j & 63, j >> 6);
    } else if (i < 13312) {
        const int j = i - 12288;
        transpose_tile(Wkvd, Wcat_t + 2048 * 2048, 2048, 512, j & 15, j >> 4);
    } else if (i < 14336) {
        const int j = i - 13312;
        transpose_tile(Wkvu, Wkvu_t, 512, 2048, j & 63, j >> 6);
    } else {
        const int j = i - 14336;
        transpose_tile(Wo, Wo_t, 2048, 2048, j & 63, j >> 6);
    }
}

// ---------------- bf16 GEMM: C[M][N] = alpha * A[M][K] @ Bt[N][K]^T ----------------
// R17: m97 128^2 structure with the sync rebuilt as a 3-deep LDS ring + counted
// vmcnt (T4): prologue stages tiles 0,1; per tile {s_waitcnt vmcnt(4); s_barrier;
// stage(kt+2)}. Tile kt+1's 4 loads stay in flight ACROSS the barrier -- removes
// the vmcnt(0) drain that __syncthreads attaches (the documented ~20% m97 ceiling
// mechanism, m131-m140: untestable with 2 buffers since the incoming tile must
// drain; the 3rd buffer is what makes counted-vmcnt legal at 1 barrier/tile).
// Ring safety: stage(kt+2) overwrites buf (kt-1)%3 whose readers all crossed the
// phase-kt barrier with ds_read data already consumed (same ledger as R14's attn
// port, correctness-proven). LDS = 3*(8+8)KB = 48KB static.
// [R16 lesson: 256^2 tiles -> 128-160 WGs = half the CUs idle; grid coverage
//  dominates per-CU schedule gains. 128^2 keeps 512-640 WGs.]
// vmcnt ledger (4 gload_lds/stage/thread): prologue 8; steady wait(4); tail wait(0).
// OUT_MODE: 0 = fp32 C, 2 = bf16 C + transposed copy Ct (per-head d-major),
// 3 = fused q/kv_down split (col<2048 -> Cv *alpha; col>=2048 -> Ct stride 512).
template <int OUT_MODE>
__global__ __launch_bounds__(256) void k_gemm_bt(const unsigned short* __restrict__ A,
                                                 const unsigned short* __restrict__ B,
                                                 void* __restrict__ Cv,
                                                 unsigned short* __restrict__ Ct,
                                                 int M, int N, int K, float alpha) {
    __shared__ alignas(16) unsigned short As[3 * 128 * 32];
    __shared__ alignas(16) unsigned short Bs[3 * 128 * 32];
    const int tid = threadIdx.x;
    const int wave = tid >> 6;
    const int lane = tid & 63;
    const int l16 = lane & 15;
    const int quad = lane >> 4;
    const int bm = blockIdx.x * 128;  // M on x: same-XCD blocks share A-panels
    const int bn = blockIdx.y * 128;
    const int wm = (wave >> 1) * 64;
    const int wn = (wave & 1) * 64;

    const f32x4 fzero = {0.f, 0.f, 0.f, 0.f};
    f32x4 acc[4][4];
#pragma unroll
    for (int i = 0; i < 4; ++i)
#pragma unroll
        for (int j = 0; j < 4; ++j) acc[i][j] = fzero;

    auto AsL = (__attribute__((address_space(3))) unsigned short*)As;
    auto BsL = (__attribute__((address_space(3))) unsigned short*)Bs;

    const int c0 = wave * 128 + lane;

    auto stage = [&](int kt32) {
        const int boff = (kt32 % 3) * (128 * 32);
        const int kt = kt32 * 32;
#pragma unroll
        for (int j = 0; j < 2; ++j) {
            const int c = c0 + j * 64;
            __builtin_amdgcn_global_load_lds(
                (const __attribute__((address_space(1))) void*)(A + (size_t)(bm + (c >> 2)) * K + kt + (c & 3) * 8),
                (__attribute__((address_space(3))) void*)(AsL + boff + c * 8), 16, 0, 0);
            __builtin_amdgcn_global_load_lds(
                (const __attribute__((address_space(1))) void*)(B + (size_t)(bn + (c >> 2)) * K + kt + (c & 3) * 8),
                (__attribute__((address_space(3))) void*)(BsL + boff + c * 8), 16, 0, 0);
        }
    };

    const int nk = K >> 5;
    stage(0);
    stage(1);
    for (int kt32 = 0; kt32 < nk; ++kt32) {
        if (kt32 + 1 < nk) { WAITVM(4); } else { WAITVM(0); }
        __builtin_amdgcn_s_barrier();
        if (kt32 + 2 < nk) stage(kt32 + 2);
        const unsigned short* Ab = As + (kt32 % 3) * (128 * 32);
        const unsigned short* Bb = Bs + (kt32 % 3) * (128 * 32);

        bf16x8 af[4], bfr[4];
#pragma unroll
        for (int mt = 0; mt < 4; ++mt)
            af[mt] = *(const bf16x8*)(Ab + (wm + mt * 16 + l16) * 32 + quad * 8);
#pragma unroll
        for (int nt = 0; nt < 4; ++nt)
            bfr[nt] = *(const bf16x8*)(Bb + (wn + nt * 16 + l16) * 32 + quad * 8);

        __builtin_amdgcn_s_setprio(1);
#pragma unroll
        for (int mt = 0; mt < 4; ++mt)
#pragma unroll
            for (int nt = 0; nt < 4; ++nt)
                acc[mt][nt] = MFMA16(af[mt], bfr[nt], acc[mt][nt]);
        __builtin_amdgcn_s_setprio(0);
    }

#pragma unroll
    for (int mt = 0; mt < 4; ++mt)
#pragma unroll
        for (int nt = 0; nt < 4; ++nt) {
            const int row0 = bm + wm + mt * 16 + quad * 4;
            const int col = bn + wn + nt * 16 + l16;
            u16x4 pk;
#pragma unroll
            for (int r = 0; r < 4; ++r) {
                const float v0 = acc[mt][nt][r];
                if (OUT_MODE == 0) {
                    ((float*)Cv)[(size_t)(row0 + r) * N + col] = v0 * alpha;
                } else if (OUT_MODE == 3) {
                    if (col < 2048)
                        ((unsigned short*)Cv)[(size_t)(row0 + r) * 2048 + col] = f2bf(v0 * alpha);
                    else
                        Ct[(size_t)(row0 + r) * 512 + (col - 2048)] = f2bf(v0);
                } else {
                    const unsigned short b = f2bf(v0 * alpha);
                    ((unsigned short*)Cv)[(size_t)(row0 + r) * N + col] = b;
                    pk[r] = b;
                }
            }
            if (OUT_MODE == 2) {
                const size_t ti =
                    ((size_t)((row0 >> 11) * (N >> 7) + (col >> 7)) * 128 + (col & 127)) * 2048 +
                    (row0 & 2047);
                *(u16x4*)(Ct + ti) = pk;
            }
        }
}

// ---------------- flash attention (R15, frozen: ~81.5us = structure ceiling) ------
// 32x32x16 MFMA on the R12 skeleton (KVBLK=64, 2-deep dbuf, __syncthreads,
// gload_lds + pre-swizzled sources). In-register P via cvt_pk + permlane32.
// [R11-R15 lessons: VALU/issue trims, gload_lds, KVBLK=32 pipeline, counted vmcnt,
//  MFMA shape -- all pin at ~82us: latency-bound at structural 2 waves/SIMD.]
// Grid (16 qt, 32 bh) XCD-chunked; 4 waves; wave owns 32 q-rows; 2 blk/CU; LDS 64K.
// Base-2 no-max softmax (log2e folded into q). Writes output IN-PLACE over Q.
__global__ __launch_bounds__(256, 2) void k_attn(const unsigned short* __restrict__ Q,
                                                 const unsigned short* __restrict__ KV,
                                                 const unsigned short* __restrict__ KVT,
                                                 unsigned short* __restrict__ O) {
    __shared__ alignas(16) unsigned short Ks[2 * 64 * 128];   // [buf][kr][d], swizzled
    __shared__ alignas(16) unsigned short Vt[2 * 128 * 64];   // [buf][d][kr], swizzled

    const int tid = threadIdx.x;
    const int wave = tid >> 6, lane = tid & 63;
    const int q31 = lane & 31;
    const int hi = lane >> 5;
    const int l8 = q31 & 7;
    const int lid = blockIdx.x + (blockIdx.y << 4);
    const int wid = ((lid & 7) << 6) + (lid >> 3);
    const int qt = wid & 15;
    const int bh = wid >> 4;
    const size_t tokbase = (size_t)(bh >> 4) * 2048;
    const int hcol = (bh & 15) * 128;
    const unsigned short* kvt_head = KVT + (size_t)bh * (128 * 2048);

    bf16x8 qf[8];
    const int qrow0 = qt * 128 + wave * 32;
    {
        const unsigned short* qp = Q + (tokbase + qrow0 + q31) * 2048 + hcol + hi * 8;
#pragma unroll
        for (int kd = 0; kd < 8; ++kd) qf[kd] = *(const bf16x8*)(qp + kd * 16);
    }

    f32x16 o_acc[4];
#pragma unroll
    for (int dt = 0; dt < 4; ++dt)
#pragma unroll
        for (int r = 0; r < 16; ++r) o_acc[dt][r] = 0.f;
    float l_i = 0.f;

    auto KsL = (__attribute__((address_space(3))) unsigned short*)Ks;
    auto VtL = (__attribute__((address_space(3))) unsigned short*)Vt;

    const int r4 = tid >> 4, cdK = tid & 15;
    const int csK = (cdK & 8) | ((cdK & 7) ^ (r4 & 7));
    const int dv = tid >> 3, cvV = tid & 7;
    const int csV = cvV ^ (dv & 7);
    const unsigned short* kp0 = KV + (tokbase + r4) * 2048 + hcol + csK * 8;
    const unsigned short* vp0 = kvt_head + (size_t)dv * 2048 + csV * 8;

    auto stage = [&](int kt) {
        auto Kb = KsL + (kt & 1) * (64 * 128) + tid * 8;
        auto Vb = VtL + (kt & 1) * (128 * 64) + tid * 8;
        const unsigned short* kp = kp0 + (size_t)kt * (64 * 2048);
        const unsigned short* vp = vp0 + kt * 64;
#pragma unroll
        for (int p = 0; p < 4; ++p) {
            __builtin_amdgcn_global_load_lds(
                (const __attribute__((address_space(1))) void*)(kp + p * (16 * 2048)),
                (__attribute__((address_space(3))) void*)(Kb + p * 2048), 16, 0, 0);
            __builtin_amdgcn_global_load_lds(
                (const __attribute__((address_space(1))) void*)(vp + (size_t)p * (32 * 2048)),
                (__attribute__((address_space(3))) void*)(Vb + p * 2048), 16, 0, 0);
        }
    };

    stage(0);

    for (int kt = 0; kt < 32; ++kt) {
        __syncthreads();
        if (kt < 31) stage(kt + 1);
        const unsigned short* Kb = Ks + (kt & 1) * (64 * 128);
        const unsigned short* Vb = Vt + (kt & 1) * (128 * 64);

        f32x16 st[2];
#pragma unroll
        for (int r = 0; r < 16; ++r) { st[0][r] = 0.f; st[1][r] = 0.f; }
        __builtin_amdgcn_s_setprio(1);
#pragma unroll
        for (int kd = 0; kd < 8; ++kd) {
            const int c = 2 * kd + hi;
            const int sw = (c & 8) | ((c & 7) ^ l8);
#pragma unroll
            for (int mt = 0; mt < 2; ++mt) {
                const bf16x8 kf = *(const bf16x8*)(Kb + (mt * 32 + q31) * 128 + sw * 8);
                st[mt] = MFMA32(kf, qf[kd], st[mt]);
            }
        }
        __builtin_amdgcn_s_setprio(0);

        bf16x8 pfrk[2][2];
#pragma unroll
        for (int mt = 0; mt < 2; ++mt) {
            float p[16];
            float rs = 0.f;
#pragma unroll
            for (int r = 0; r < 16; ++r) {
                p[r] = fexp2(st[mt][r]);
                rs += p[r];
            }
            l_i += rs;
#pragma unroll
            for (int s = 0; s < 2; ++s) {
                unsigned int w0, w1, w2, w3;
                asm("v_cvt_pk_bf16_f32 %0, %1, %2" : "=v"(w0) : "v"(p[s * 8 + 0]), "v"(p[s * 8 + 1]));
                asm("v_cvt_pk_bf16_f32 %0, %1, %2" : "=v"(w1) : "v"(p[s * 8 + 2]), "v"(p[s * 8 + 3]));
                asm("v_cvt_pk_bf16_f32 %0, %1, %2" : "=v"(w2) : "v"(p[s * 8 + 4]), "v"(p[s * 8 + 5]));
                asm("v_cvt_pk_bf16_f32 %0, %1, %2" : "=v"(w3) : "v"(p[s * 8 + 6]), "v"(p[s * 8 + 7]));
                const u32x2 u02 = plswap32(w0, w2);
                const u32x2 u13 = plswap32(w1, w3);
                const u32x4 w = {u02.x, u13.x, u02.y, u13.y};
                pfrk[mt][s] = __builtin_bit_cast(bf16x8, w);
            }
        }

        __builtin_amdgcn_s_setprio(1);
#pragma unroll
        for (int ks = 0; ks < 4; ++ks) {
            const int swv = ((2 * ks + hi) ^ l8) * 8;
            const bf16x8 pf = pfrk[ks >> 1][ks & 1];
#pragma unroll
            for (int dt = 0; dt < 4; ++dt) {
                const bf16x8 vf = *(const bf16x8*)(Vb + (dt * 32 + q31) * 64 + swv);
                o_acc[dt] = MFMA32(vf, pf, o_acc[dt]);
            }
        }
        __builtin_amdgcn_s_setprio(0);
    }

    {
        const u32x2 a = plswap32(__float_as_uint(l_i), __float_as_uint(l_i));
        const float inv = 1.0f / (__uint_as_float(a.x) + __uint_as_float(a.y));
        unsigned short* dst = O + (tokbase + qrow0 + q31) * 2048 + hcol + hi * 4;
#pragma unroll
        for (int dt = 0; dt < 4; ++dt)
#pragma unroll
            for (int g = 0; g < 4; ++g) {
                u16x4 pk;
#pragma unroll
                for (int j = 0; j < 4; ++j) pk[j] = f2bf(o_acc[dt][g * 4 + j] * inv);
                *(u16x4*)(dst + dt * 32 + g * 8) = pk;
            }
    }
}

// ---------------- host launcher ----------------
extern "C" void kernel_launch(void* const* d_in, const int* in_sizes, int n_in,
                              void* d_out, int out_size, void* d_ws, size_t ws_size,
                              hipStream_t stream) {
    const float* x = (const float*)d_in[0];
    const float* W_q = (const float*)d_in[1];
    const float* W_kvd = (const float*)d_in[2];
    const float* W_kvu = (const float*)d_in[3];
    const float* W_o = (const float*)d_in[4];

    // 72 MB workspace (lifetime-packed):
    //   [0,16M)   xb (dead after fused GEMM) -> kvT
    //   [16,32M)  qb (q; attn writes output in-place here)
    //   [32,48M)  kvb
    //   [48,56M)  Wo_t
    //   [56,66M)  Wcat_t [2560][2048] (dead after fused GEMM)
    //   [66,68M)  Wkvu_t
    //   [68,72M)  lat
    char* w = (char*)d_ws;
    unsigned short* xb = (unsigned short*)(w);
    unsigned short* kvT = xb;
    unsigned short* qb = (unsigned short*)(w + (size_t)16 * 1024 * 1024);
    unsigned short* kvb = (unsigned short*)(w + (size_t)32 * 1024 * 1024);
    unsigned short* Wo_t = (unsigned short*)(w + (size_t)48 * 1024 * 1024);
    unsigned short* Wcat_t = (unsigned short*)(w + (size_t)56 * 1024 * 1024);
    unsigned short* Wkvu_t = (unsigned short*)(w + (size_t)66 * 1024 * 1024);
    unsigned short* lat = (unsigned short*)(w + (size_t)68 * 1024 * 1024);

    // fused prep: x->bf16 + all weight transposes (one dispatch)
    k_prep<<<18432, 256, 0, stream>>>(x, W_q, W_kvd, W_kvu, W_o, xb, Wcat_t, Wkvu_t, Wo_t);

    // fused: q = (x@W_q)*(scale*log2e) -> qb ; latent = x@W_kv_down -> lat
    // alpha = log2(e)/sqrt(128): attn uses exp2 directly (exp fold).
    k_gemm_bt<3><<<dim3(32, 20), 256, 0, stream>>>(xb, Wcat_t, qb, lat, 4096, 2560, 2048,
                                                   0.12751743f);
    // kv = latent @ W_kv_up  (+ per-head transposed copy kvT; xb is dead now)
    k_gemm_bt<2><<<dim3(32, 16), 256, 0, stream>>>(lat, Wkvu_t, kvb, kvT, 4096, 2048, 512,
                                                   1.0f);
    // flash attention (output in-place over qb); R15 config (frozen)
    k_attn<<<dim3(16, 32), 256, 0, stream>>>(qb, kvb, kvT, qb);
    // out = attn @ W_o  (fp32 output)
    k_gemm_bt<0><<<dim3(32, 16), 256, 0, stream>>>(qb, Wo_t, d_out, nullptr, 4096, 2048, 2048,
                                                   1.0f);
}

// Round 11
// 304.338 us; speedup vs baseline: 1.0630x; 1.0283x over previous
//
#include <hip/hip_runtime.h>

typedef __attribute__((ext_vector_type(8))) __bf16 bf16x8;
typedef __attribute__((ext_vector_type(4))) float f32x4;
typedef __attribute__((ext_vector_type(16))) float f32x16;
typedef __attribute__((ext_vector_type(8))) unsigned short u16x8;
typedef __attribute__((ext_vector_type(4))) unsigned short u16x4;
typedef __attribute__((ext_vector_type(2))) unsigned int u32x2;
typedef __attribute__((ext_vector_type(4))) unsigned int u32x4;

#define MFMA16(a, b, c) __builtin_amdgcn_mfma_f32_16x16x32_bf16((a), (b), (c), 0, 0, 0)
#define MFMA32(a, b, c) __builtin_amdgcn_mfma_f32_32x32x16_bf16((a), (b), (c), 0, 0, 0)

__device__ __forceinline__ unsigned short f2bf(float f) {
    unsigned int u = __float_as_uint(f);
    unsigned int r = (u + 0x7FFFu + ((u >> 16) & 1u)) >> 16;
    return (unsigned short)r;
}

__device__ __forceinline__ float fexp2(float x) {
#if __has_builtin(__builtin_amdgcn_exp2f)
    return __builtin_amdgcn_exp2f(x);
#else
    return exp2f(x);
#endif
}

// gfx950 lane-swap primitives (half-wave data movement without LDS).
__device__ __forceinline__ u32x2 plswap32(unsigned int x, unsigned int y) {
#if __has_builtin(__builtin_amdgcn_permlane32_swap)
    return __builtin_amdgcn_permlane32_swap(x, y, false, false);
#else
    asm volatile("s_nop 1\n\tv_permlane32_swap_b32 %0, %1" : "+v"(x), "+v"(y));
    u32x2 r = {x, y};
    return r;
#endif
}

// ---------------- fused prep: x->bf16 convert + 4 weight transposes ----------------
__device__ __forceinline__ void transpose_tile(const float* __restrict__ in,
                                               unsigned short* __restrict__ out,
                                               int R, int C, int bx, int by) {
    __shared__ float tile[32][33];
    const int tx = threadIdx.x & 31, ty = threadIdx.x >> 5;
    const int c0 = bx * 32, r0 = by * 32;
#pragma unroll
    for (int i = 0; i < 4; ++i)
        tile[ty + i * 8][tx] = in[(size_t)(r0 + ty + i * 8) * C + c0 + tx];
    __syncthreads();
#pragma unroll
    for (int i = 0; i < 4; ++i)
        out[(size_t)(c0 + ty + i * 8) * R + r0 + tx] = f2bf(tile[tx][ty + i * 8]);
}

__global__ __launch_bounds__(256) void k_prep(const float* __restrict__ x,
                                              const float* __restrict__ Wq,
                                              const float* __restrict__ Wkvd,
                                              const float* __restrict__ Wkvu,
                                              const float* __restrict__ Wo,
                                              unsigned short* __restrict__ xb,
                                              unsigned short* __restrict__ Wcat_t,
                                              unsigned short* __restrict__ Wkvu_t,
                                              unsigned short* __restrict__ Wo_t) {
    const int i = blockIdx.x;
    if (i < 8192) {
        const int idx = i * 256 + threadIdx.x;
        const float4 v = ((const float4*)x)[idx];
        u16x4 o = { f2bf(v.x), f2bf(v.y), f2bf(v.z), f2bf(v.w) };
        ((u16x4*)xb)[idx] = o;
    } else if (i < 12288) {
        const int j = i - 8192;
        transpose_tile(Wq, Wcat_t, 2048, 2048, j & 63, j >> 6);
    } else if (i < 13312) {
        const int j = i - 12288;
        transpose_tile(Wkvd, Wcat_t + 2048 * 2048, 2048, 512, j & 15, j >> 4);
    } else if (i < 14336) {
        const int j = i - 13312;
        transpose_tile(Wkvu, Wkvu_t, 512, 2048, j & 63, j >> 6);
    } else {
        const int j = i - 14336;
        transpose_tile(Wo, Wo_t, 2048, 2048, j & 63, j >> 6);
    }
}

// ---------------- bf16 GEMM: C[M][N] = alpha * A[M][K] @ Bt[N][K]^T ----------------
// m97 128^2 structure, 2-deep dbuf (proven R12/R15 base; R17's 3-ring was null --
// cross-block overlap at 2.5-3 blk/CU already hides the per-block drain, m114).
// OUT_MODE: 0 = fp32 C, 2 = bf16 C + transposed kvT copy via LDS-transpose epilogue
// (R18: replaces the 8B/lane 4KB-strided scatter -- ~8x write amplification on a
//  16MB tensor -- with swizzled LDS stash + 256B-contiguous coalesced row writes;
//  As+Bs = exactly one 128x128 bf16 tile after the K-loop),
// 3 = fused q/kv_down split (col<2048 -> Cv *alpha; col>=2048 -> Ct stride 512).
template <int OUT_MODE>
__global__ __launch_bounds__(256) void k_gemm_bt(const unsigned short* __restrict__ A,
                                                 const unsigned short* __restrict__ B,
                                                 void* __restrict__ Cv,
                                                 unsigned short* __restrict__ Ct,
                                                 int M, int N, int K, float alpha) {
    __shared__ alignas(16) unsigned short smem[2 * 128 * 32 * 2];  // As | Bs (| T)
    unsigned short* As = smem;
    unsigned short* Bs = smem + 2 * 128 * 32;
    const int tid = threadIdx.x;
    const int wave = tid >> 6;
    const int lane = tid & 63;
    const int l16 = lane & 15;
    const int quad = lane >> 4;
    const int bm = blockIdx.x * 128;  // M on x: same-XCD blocks share A-panels
    const int bn = blockIdx.y * 128;
    const int wm = (wave >> 1) * 64;
    const int wn = (wave & 1) * 64;

    const f32x4 fzero = {0.f, 0.f, 0.f, 0.f};
    f32x4 acc[4][4];
#pragma unroll
    for (int i = 0; i < 4; ++i)
#pragma unroll
        for (int j = 0; j < 4; ++j) acc[i][j] = fzero;

    auto AsL = (__attribute__((address_space(3))) unsigned short*)As;
    auto BsL = (__attribute__((address_space(3))) unsigned short*)Bs;

    const int c0 = wave * 128 + lane;

    auto stage = [&](int kt32) {
        const int boff = (kt32 & 1) * (128 * 32);
        const int kt = kt32 * 32;
#pragma unroll
        for (int j = 0; j < 2; ++j) {
            const int c = c0 + j * 64;
            __builtin_amdgcn_global_load_lds(
                (const __attribute__((address_space(1))) void*)(A + (size_t)(bm + (c >> 2)) * K + kt + (c & 3) * 8),
                (__attribute__((address_space(3))) void*)(AsL + boff + c * 8), 16, 0, 0);
            __builtin_amdgcn_global_load_lds(
                (const __attribute__((address_space(1))) void*)(B + (size_t)(bn + (c >> 2)) * K + kt + (c & 3) * 8),
                (__attribute__((address_space(3))) void*)(BsL + boff + c * 8), 16, 0, 0);
        }
    };

    const int nk = K >> 5;
    stage(0);
    for (int kt32 = 0; kt32 < nk; ++kt32) {
        __syncthreads();
        if (kt32 + 1 < nk) stage(kt32 + 1);
        const unsigned short* Ab = As + (kt32 & 1) * (128 * 32);
        const unsigned short* Bb = Bs + (kt32 & 1) * (128 * 32);

        bf16x8 af[4], bfr[4];
#pragma unroll
        for (int mt = 0; mt < 4; ++mt)
            af[mt] = *(const bf16x8*)(Ab + (wm + mt * 16 + l16) * 32 + quad * 8);
#pragma unroll
        for (int nt = 0; nt < 4; ++nt)
            bfr[nt] = *(const bf16x8*)(Bb + (wn + nt * 16 + l16) * 32 + quad * 8);

        __builtin_amdgcn_s_setprio(1);
#pragma unroll
        for (int mt = 0; mt < 4; ++mt)
#pragma unroll
            for (int nt = 0; nt < 4; ++nt)
                acc[mt][nt] = MFMA16(af[mt], bfr[nt], acc[mt][nt]);
        __builtin_amdgcn_s_setprio(0);
    }

    if (OUT_MODE == 2) {
        // ---- LDS-transpose epilogue: C write (coalesced) + swizzled LDS stash ----
        __syncthreads();  // all waves' final frag reads done -> smem reusable
        unsigned short* T = smem;  // [col d 0..127][tok 0..127], tok ^= (d&7)<<4
#pragma unroll
        for (int mt = 0; mt < 4; ++mt)
#pragma unroll
            for (int nt = 0; nt < 4; ++nt) {
                const int rl = wm + mt * 16 + quad * 4;  // local token row
                const int cl = wn + nt * 16 + l16;       // local col (d)
                u16x4 pk;
#pragma unroll
                for (int r = 0; r < 4; ++r) {
                    const unsigned short b = f2bf(acc[mt][nt][r] * alpha);
                    ((unsigned short*)Cv)[(size_t)(bm + rl + r) * N + bn + cl] = b;
                    pk[r] = b;
                }
                // 8B write; banks: (tok'>>1)&31 varies w/ cl&7 -> 2-way = free
                *(u16x4*)(T + cl * 128 + (rl ^ ((cl & 7) << 4))) = pk;
            }
        __syncthreads();
        // ---- coalesced kvT rows: 256B contiguous per d, 16B/lane ----
        const int head = bn >> 7;   // N=2048: one 128-col tile == one head
        const int batch = bm >> 11;
        unsigned short* kb = Ct + (size_t)(batch * 16 + head) * (128 * 2048) + (bm & 2047);
#pragma unroll
        for (int it = 0; it < 8; ++it) {
            const int slot = it * 256 + tid;
            const int d = slot >> 4;
            const int ch = (slot & 15) * 8;  // token chunk (8 elems)
            const u16x8 v = *(const u16x8*)(T + d * 128 + (ch ^ ((d & 7) << 4)));
            *(u16x8*)(kb + (size_t)d * 2048 + ch) = v;
        }
    } else {
#pragma unroll
        for (int mt = 0; mt < 4; ++mt)
#pragma unroll
            for (int nt = 0; nt < 4; ++nt) {
                const int row0 = bm + wm + mt * 16 + quad * 4;
                const int col = bn + wn + nt * 16 + l16;
#pragma unroll
                for (int r = 0; r < 4; ++r) {
                    const float v0 = acc[mt][nt][r];
                    if (OUT_MODE == 0) {
                        ((float*)Cv)[(size_t)(row0 + r) * N + col] = v0 * alpha;
                    } else {  // OUT_MODE == 3
                        if (col < 2048)
                            ((unsigned short*)Cv)[(size_t)(row0 + r) * 2048 + col] = f2bf(v0 * alpha);
                        else
                            Ct[(size_t)(row0 + r) * 512 + (col - 2048)] = f2bf(v0);
                    }
                }
            }
    }
}

// ---------------- flash attention (R15, frozen: ~80.5us = structure ceiling) ------
// 32x32x16 MFMA on the R12 skeleton (KVBLK=64, 2-deep dbuf, __syncthreads,
// gload_lds + pre-swizzled sources). In-register P via cvt_pk + permlane32.
// [R11-R15 lessons: VALU/issue trims, gload_lds, KVBLK=32 pipeline, counted vmcnt,
//  MFMA shape -- all pin at ~82us: latency-bound at structural 2 waves/SIMD.]
// Grid (16 qt, 32 bh) XCD-chunked; 4 waves; wave owns 32 q-rows; 2 blk/CU; LDS 64K.
// Base-2 no-max softmax (log2e folded into q). Writes output IN-PLACE over Q.
__global__ __launch_bounds__(256, 2) void k_attn(const unsigned short* __restrict__ Q,
                                                 const unsigned short* __restrict__ KV,
                                                 const unsigned short* __restrict__ KVT,
                                                 unsigned short* __restrict__ O) {
    __shared__ alignas(16) unsigned short Ks[2 * 64 * 128];   // [buf][kr][d], swizzled
    __shared__ alignas(16) unsigned short Vt[2 * 128 * 64];   // [buf][d][kr], swizzled

    const int tid = threadIdx.x;
    const int wave = tid >> 6, lane = tid & 63;
    const int q31 = lane & 31;
    const int hi = lane >> 5;
    const int l8 = q31 & 7;
    const int lid = blockIdx.x + (blockIdx.y << 4);
    const int wid = ((lid & 7) << 6) + (lid >> 3);
    const int qt = wid & 15;
    const int bh = wid >> 4;
    const size_t tokbase = (size_t)(bh >> 4) * 2048;
    const int hcol = (bh & 15) * 128;
    const unsigned short* kvt_head = KVT + (size_t)bh * (128 * 2048);

    bf16x8 qf[8];
    const int qrow0 = qt * 128 + wave * 32;
    {
        const unsigned short* qp = Q + (tokbase + qrow0 + q31) * 2048 + hcol + hi * 8;
#pragma unroll
        for (int kd = 0; kd < 8; ++kd) qf[kd] = *(const bf16x8*)(qp + kd * 16);
    }

    f32x16 o_acc[4];
#pragma unroll
    for (int dt = 0; dt < 4; ++dt)
#pragma unroll
        for (int r = 0; r < 16; ++r) o_acc[dt][r] = 0.f;
    float l_i = 0.f;

    auto KsL = (__attribute__((address_space(3))) unsigned short*)Ks;
    auto VtL = (__attribute__((address_space(3))) unsigned short*)Vt;

    const int r4 = tid >> 4, cdK = tid & 15;
    const int csK = (cdK & 8) | ((cdK & 7) ^ (r4 & 7));
    const int dv = tid >> 3, cvV = tid & 7;
    const int csV = cvV ^ (dv & 7);
    const unsigned short* kp0 = KV + (tokbase + r4) * 2048 + hcol + csK * 8;
    const unsigned short* vp0 = kvt_head + (size_t)dv * 2048 + csV * 8;

    auto stage = [&](int kt) {
        auto Kb = KsL + (kt & 1) * (64 * 128) + tid * 8;
        auto Vb = VtL + (kt & 1) * (128 * 64) + tid * 8;
        const unsigned short* kp = kp0 + (size_t)kt * (64 * 2048);
        const unsigned short* vp = vp0 + kt * 64;
#pragma unroll
        for (int p = 0; p < 4; ++p) {
            __builtin_amdgcn_global_load_lds(
                (const __attribute__((address_space(1))) void*)(kp + p * (16 * 2048)),
                (__attribute__((address_space(3))) void*)(Kb + p * 2048), 16, 0, 0);
            __builtin_amdgcn_global_load_lds(
                (const __attribute__((address_space(1))) void*)(vp + (size_t)p * (32 * 2048)),
                (__attribute__((address_space(3))) void*)(Vb + p * 2048), 16, 0, 0);
        }
    };

    stage(0);

    for (int kt = 0; kt < 32; ++kt) {
        __syncthreads();
        if (kt < 31) stage(kt + 1);
        const unsigned short* Kb = Ks + (kt & 1) * (64 * 128);
        const unsigned short* Vb = Vt + (kt & 1) * (128 * 64);

        f32x16 st[2];
#pragma unroll
        for (int r = 0; r < 16; ++r) { st[0][r] = 0.f; st[1][r] = 0.f; }
        __builtin_amdgcn_s_setprio(1);
#pragma unroll
        for (int kd = 0; kd < 8; ++kd) {
            const int c = 2 * kd + hi;
            const int sw = (c & 8) | ((c & 7) ^ l8);
#pragma unroll
            for (int mt = 0; mt < 2; ++mt) {
                const bf16x8 kf = *(const bf16x8*)(Kb + (mt * 32 + q31) * 128 + sw * 8);
                st[mt] = MFMA32(kf, qf[kd], st[mt]);
            }
        }
        __builtin_amdgcn_s_setprio(0);

        bf16x8 pfrk[2][2];
#pragma unroll
        for (int mt = 0; mt < 2; ++mt) {
            float p[16];
            float rs = 0.f;
#pragma unroll
            for (int r = 0; r < 16; ++r) {
                p[r] = fexp2(st[mt][r]);
                rs += p[r];
            }
            l_i += rs;
#pragma unroll
            for (int s = 0; s < 2; ++s) {
                unsigned int w0, w1, w2, w3;
                asm("v_cvt_pk_bf16_f32 %0, %1, %2" : "=v"(w0) : "v"(p[s * 8 + 0]), "v"(p[s * 8 + 1]));
                asm("v_cvt_pk_bf16_f32 %0, %1, %2" : "=v"(w1) : "v"(p[s * 8 + 2]), "v"(p[s * 8 + 3]));
                asm("v_cvt_pk_bf16_f32 %0, %1, %2" : "=v"(w2) : "v"(p[s * 8 + 4]), "v"(p[s * 8 + 5]));
                asm("v_cvt_pk_bf16_f32 %0, %1, %2" : "=v"(w3) : "v"(p[s * 8 + 6]), "v"(p[s * 8 + 7]));
                const u32x2 u02 = plswap32(w0, w2);
                const u32x2 u13 = plswap32(w1, w3);
                const u32x4 w = {u02.x, u13.x, u02.y, u13.y};
                pfrk[mt][s] = __builtin_bit_cast(bf16x8, w);
            }
        }

        __builtin_amdgcn_s_setprio(1);
#pragma unroll
        for (int ks = 0; ks < 4; ++ks) {
            const int swv = ((2 * ks + hi) ^ l8) * 8;
            const bf16x8 pf = pfrk[ks >> 1][ks & 1];
#pragma unroll
            for (int dt = 0; dt < 4; ++dt) {
                const bf16x8 vf = *(const bf16x8*)(Vb + (dt * 32 + q31) * 64 + swv);
                o_acc[dt] = MFMA32(vf, pf, o_acc[dt]);
            }
        }
        __builtin_amdgcn_s_setprio(0);
    }

    {
        const u32x2 a = plswap32(__float_as_uint(l_i), __float_as_uint(l_i));
        const float inv = 1.0f / (__uint_as_float(a.x) + __uint_as_float(a.y));
        unsigned short* dst = O + (tokbase + qrow0 + q31) * 2048 + hcol + hi * 4;
#pragma unroll
        for (int dt = 0; dt < 4; ++dt)
#pragma unroll
            for (int g = 0; g < 4; ++g) {
                u16x4 pk;
#pragma unroll
                for (int j = 0; j < 4; ++j) pk[j] = f2bf(o_acc[dt][g * 4 + j] * inv);
                *(u16x4*)(dst + dt * 32 + g * 8) = pk;
            }
    }
}

// ---------------- host launcher ----------------
extern "C" void kernel_launch(void* const* d_in, const int* in_sizes, int n_in,
                              void* d_out, int out_size, void* d_ws, size_t ws_size,
                              hipStream_t stream) {
    const float* x = (const float*)d_in[0];
    const float* W_q = (const float*)d_in[1];
    const float* W_kvd = (const float*)d_in[2];
    const float* W_kvu = (const float*)d_in[3];
    const float* W_o = (const float*)d_in[4];

    // 72 MB workspace (lifetime-packed):
    //   [0,16M)   xb (dead after fused GEMM) -> kvT
    //   [16,32M)  qb (q; attn writes output in-place here)
    //   [32,48M)  kvb
    //   [48,56M)  Wo_t
    //   [56,66M)  Wcat_t [2560][2048] (dead after fused GEMM)
    //   [66,68M)  Wkvu_t
    //   [68,72M)  lat
    char* w = (char*)d_ws;
    unsigned short* xb = (unsigned short*)(w);
    unsigned short* kvT = xb;
    unsigned short* qb = (unsigned short*)(w + (size_t)16 * 1024 * 1024);
    unsigned short* kvb = (unsigned short*)(w + (size_t)32 * 1024 * 1024);
    unsigned short* Wo_t = (unsigned short*)(w + (size_t)48 * 1024 * 1024);
    unsigned short* Wcat_t = (unsigned short*)(w + (size_t)56 * 1024 * 1024);
    unsigned short* Wkvu_t = (unsigned short*)(w + (size_t)66 * 1024 * 1024);
    unsigned short* lat = (unsigned short*)(w + (size_t)68 * 1024 * 1024);

    // fused prep: x->bf16 + all weight transposes (one dispatch)
    k_prep<<<18432, 256, 0, stream>>>(x, W_q, W_kvd, W_kvu, W_o, xb, Wcat_t, Wkvu_t, Wo_t);

    // fused: q = (x@W_q)*(scale*log2e) -> qb ; latent = x@W_kv_down -> lat
    // alpha = log2(e)/sqrt(128): attn uses exp2 directly (exp fold).
    k_gemm_bt<3><<<dim3(32, 20), 256, 0, stream>>>(xb, Wcat_t, qb, lat, 4096, 2560, 2048,
                                                   0.12751743f);
    // kv = latent @ W_kv_up  (+ kvT via LDS-transpose coalesced epilogue; xb dead)
    k_gemm_bt<2><<<dim3(32, 16), 256, 0, stream>>>(lat, Wkvu_t, kvb, kvT, 4096, 2048, 512,
                                                   1.0f);
    // flash attention (output in-place over qb); R15 config (frozen)
    k_attn<<<dim3(16, 32), 256, 0, stream>>>(qb, kvb, kvT, qb);
    // out = attn @ W_o  (fp32 output)
    k_gemm_bt<0><<<dim3(32, 16), 256, 0, stream>>>(qb, Wo_t, d_out, nullptr, 4096, 2048, 2048,
                                                   1.0f);
}